// Round 19
// baseline (77.048 us; speedup 1.0000x reference)
//
#include <hip/hip_runtime.h>

#define NB 8
#define DM 256
#define FD 96
#define SLD 104   // f16 stride of phys staging row (208B, 16B-aligned)

using half8 = _Float16 __attribute__((ext_vector_type(8)));
using half4 = _Float16 __attribute__((ext_vector_type(4)));
using f32x4 = float __attribute__((ext_vector_type(4)));
using f2    = float __attribute__((ext_vector_type(2)));

// clamp(x,0,1) as a single v_med3_f32 (exact for non-NaN x, which holds here)
__device__ __forceinline__ float clamp01(float x) {
    return __builtin_amdgcn_fmed3f(x, 0.0f, 1.0f);
}

// lane-xor-1 exchange as DPP quad_perm(1,0,3,2): 1 VALU inst, no LDS/waitcnt.
__device__ __forceinline__ float dpp_swap1(float x) {
    return __builtin_bit_cast(float,
        __builtin_amdgcn_mov_dpp(__builtin_bit_cast(int, x), 0xB1, 0xF, 0xF, true));
}

// ---------------------------------------------------------------------------
// Kernel 0: precompute B = lin_w^T as f16 MFMA fragments into d_ws (48 KB).
// ---------------------------------------------------------------------------
__global__ void bprep_kernel(const float* __restrict__ lin_w,
                             _Float16* __restrict__ Bpre)
{
    const int fb = blockIdx.x * 256 + threadIdx.x;     // 0..3071
    const int ks = fb >> 10, nbv = (fb >> 6) & 15, ll = fb & 63;
    const float* lwrow = lin_w + (size_t)(nbv * 16 + (ll & 15)) * FD
                               + (ks * 32 + 4 * (ll >> 4));
    float4 lo = *reinterpret_cast<const float4*>(lwrow);
    float4 hi = *reinterpret_cast<const float4*>(lwrow + 16);
    half8 v;
    v[0] = (_Float16)lo.x; v[1] = (_Float16)lo.y; v[2] = (_Float16)lo.z; v[3] = (_Float16)lo.w;
    v[4] = (_Float16)hi.x; v[5] = (_Float16)hi.y; v[6] = (_Float16)hi.z; v[7] = (_Float16)hi.w;
    *reinterpret_cast<half8*>(Bpre + (size_t)fb * 8) = v;
}

// ---------------------------------------------------------------------------
// Fused kernel = r18 (71.3us, absmax 0.0078125) with two bit-exact trims:
//  1) clamp01 -> v_med3_f32 (1 inst vs max+min; ~44 clamps/step/thread)
//  2) h/W f32 outputs stored DIRECTLY from registers (removes the LDS
//     readback: 12 ds_read_b64 + cvts/thread; h/W outputs now exact f32).
//     W column order handled address-side: own-half pair at +co_own,
//     other-half pair at +co_oth -> zero selects.
// S staging retained only for einsum A-fragments. Sim math untouched.
// ---------------------------------------------------------------------------
__global__ __launch_bounds__(256, 3) void fused_kernel(
    const int* __restrict__ bits,
    const float* __restrict__ stim_in,
    const float* __restrict__ Winit,
    const int* __restrict__ steps_ptr,
    const _Float16* __restrict__ Bpre,
    const float* __restrict__ lin_b,
    float* __restrict__ out_emb,
    float* __restrict__ out_h,
    float* __restrict__ out_W)
{
    __shared__ __align__(16) char smem[64 * 132 * 4];   // 33792 B union
    _Float16* S    = reinterpret_cast<_Float16*>(smem); // [128][SLD] staging
    float*    Cbuf = reinterpret_cast<float*>(smem);    // [64][132] overlay

    const int tid  = threadIdx.x;
    const int pos0 = blockIdx.x * 128;
    const int p    = tid >> 1;
    const int pos  = pos0 + p;
    const int sub  = tid & 1;
    const int steps = steps_ptr[0];

    // local order: blocks 0..3 own half, 4..7 partner half
    f2 hA[8];        // (E,P) per block
    f2 hB[8];        // (G,L) per block
    f2 W2[4][4];     // own 4 rows x 4 local col-pairs

    // ---- decode own 4 blocks
    const int4* bp = reinterpret_cast<const int4*>(bits + (size_t)pos * 64 + sub * 32);
    #pragma unroll
    for (int b = 0; b < 4; ++b) {
        int4 lo = bp[2 * b + 0];
        int4 hi = bp[2 * b + 1];
        hA[b].x = (float)(lo.x * 2 + lo.y) / 3.0f;
        hA[b].y = (float)(lo.z * 2 + lo.w) / 3.0f;
        hB[b].x = (float)(hi.x * 2 + hi.y) / 3.0f;
        hB[b].y = (float)(hi.z * 2 + hi.w) / 3.0f;
    }
    #pragma unroll
    for (int b = 0; b < 4; ++b) {
        hA[4 + b].x = dpp_swap1(hA[b].x);
        hA[4 + b].y = dpp_swap1(hA[b].y);
        hB[4 + b].x = dpp_swap1(hB[b].x);
        hB[4 + b].y = dpp_swap1(hB[b].y);
    }

    const int co_own = sub * 4;
    const int co_oth = 4 - sub * 4;
    #pragma unroll
    for (int i = 0; i < 4; ++i) {
        const float* rowp = Winit + (size_t)pos * 64 + (size_t)(co_own + i) * 8;
        float4 a = *reinterpret_cast<const float4*>(rowp + co_own);
        float4 b = *reinterpret_cast<const float4*>(rowp + co_oth);
        W2[i][0] = (f2){a.x, a.y};
        W2[i][1] = (f2){a.z, a.w};
        W2[i][2] = (f2){b.x, b.y};
        W2[i][3] = (f2){b.z, b.w};
        if (i & 1) W2[i][i >> 1].y = 0.0f; else W2[i][i >> 1].x = 0.0f;  // diag
    }

    const float stim = stim_in[pos];

    // lex index of (a,b), a<b, in 0..3 (folds at compile time under unroll)
    constexpr int LEXT[4][4] = {{9,0,1,2},{9,9,3,4},{9,9,9,5},{9,9,9,9}};

    for (int st = 0; st < steps; ++st) {
        // ---- neigh: packed fma chains, per-channel order j=0..7 (== r14)
        f2 nbA[4], nbB[4];
        #pragma unroll
        for (int i = 0; i < 4; ++i) {
            f2 sA = {0.f, 0.f}, sB = {0.f, 0.f};
            #pragma unroll
            for (int jc = 0; jc < 4; ++jc) {
                f2 wv = W2[i][jc];
                f2 w0 = {wv.x, wv.x};
                f2 w1 = {wv.y, wv.y};
                sA = __builtin_elementwise_fma(w0, hA[2 * jc],     sA);
                sA = __builtin_elementwise_fma(w1, hA[2 * jc + 1], sA);
                sB = __builtin_elementwise_fma(w0, hB[2 * jc],     sB);
                sB = __builtin_elementwise_fma(w1, hB[2 * jc + 1], sB);
            }
            float tw = W2[i][0].x; tw += W2[i][0].y;
            tw += W2[i][1].x;      tw += W2[i][1].y;
            tw += W2[i][2].x;      tw += W2[i][2].y;
            tw += W2[i][3].x;      tw += W2[i][3].y;
            float inv = __builtin_amdgcn_rcpf(tw + 1e-8f);
            f2 inv2 = {inv, inv};
            nbA[i] = sA * inv2;
            nbB[i] = sB * inv2;
        }
        // ---- h update (scalar verbatim r14; clamp01 is now med3)
        #pragma unroll
        for (int i = 0; i < 4; ++i) {
            float E = hA[i].x, P = hA[i].y, G = hB[i].x, L = hB[i].y;
            float En = nbA[i].x, Pn = nbA[i].y, Gn = nbB[i].x, Ln = nbB[i].y;
            float E_new = clamp01(E + 0.3f * stim - 0.4f * P - 0.2f * G);
            float P_new = clamp01(P + 0.5f * stim + 0.3f * (Pn - P) - 0.2f * E);
            float G_new = clamp01(G + 0.4f * E * (1.0f - P) + 0.2f * (Gn - G) - 0.3f * P);
            float good  = 0.5f * En + 0.5f * Gn;
            float L_new = clamp01(L + 0.4f * good + 0.3f * (Ln - L) - 0.3f * P);
            hA[i] = (f2){E_new, P_new};
            hB[i] = (f2){G_new, L_new};
        }
        // mirror partner's updated half (DPP, VALU-only)
        #pragma unroll
        for (int b = 0; b < 4; ++b) {
            hA[4 + b].x = dpp_swap1(hA[b].x);
            hA[4 + b].y = dpp_swap1(hA[b].y);
            hB[4 + b].x = dpp_swap1(hB[b].x);
            hB[4 + b].y = dpp_swap1(hB[b].y);
        }

        // ---- W update (every entry updated once; incs bit-identical to r14)
        // (a) intra-half pairs: 6, both sides owned
        #pragma unroll
        for (int i = 0; i < 4; ++i) {
            #pragma unroll
            for (int j = i + 1; j < 4; ++j) {
                float d0 = hA[i].x - hA[j].x;
                float d1 = hA[i].y - hA[j].y;
                float d2 = hB[i].x - hB[j].x;
                float d3 = hB[i].y - hB[j].y;
                float q = d0 * d0 + d1 * d1 + d2 * d2 + d3 * d3;
                float dist = __builtin_amdgcn_sqrtf(q);
                float inc = 0.1f * (0.5f * (hB[i].y + hB[j].y)) * dist;
                float wij = (j & 1) ? W2[i][j >> 1].y : W2[i][j >> 1].x;
                wij = clamp01(wij + inc - 0.05f * wij);
                if (j & 1) W2[i][j >> 1].y = wij; else W2[i][j >> 1].x = wij;
                float wji = (i & 1) ? W2[j][i >> 1].y : W2[j][i >> 1].x;
                wji = clamp01(wji + inc - 0.05f * wji);
                if (i & 1) W2[j][i >> 1].y = wji; else W2[j][i >> 1].x = wji;
            }
        }
        // (b) cross diagonal (u, u+4): same global pair on both lanes
        #pragma unroll
        for (int u = 0; u < 4; ++u) {
            const int j = u + 4;
            float d0 = hA[u].x - hA[j].x;
            float d1 = hA[u].y - hA[j].y;
            float d2 = hB[u].x - hB[j].x;
            float d3 = hB[u].y - hB[j].y;
            float q = d0 * d0 + d1 * d1 + d2 * d2 + d3 * d3;
            float dist = __builtin_amdgcn_sqrtf(q);
            float inc = 0.1f * (0.5f * (hB[u].y + hB[j].y)) * dist;
            float wij = (j & 1) ? W2[u][j >> 1].y : W2[u][j >> 1].x;
            wij = clamp01(wij + inc - 0.05f * wij);
            if (j & 1) W2[u][j >> 1].y = wij; else W2[u][j >> 1].x = wij;
        }
        // (c) cross off-diagonal: compute u<v (6), update own row, keep inc
        float cinc[6];
        #pragma unroll
        for (int u = 0; u < 4; ++u) {
            #pragma unroll
            for (int v = u + 1; v < 4; ++v) {
                const int k = LEXT[u][v];
                const int j = v + 4;
                float d0 = hA[u].x - hA[j].x;
                float d1 = hA[u].y - hA[j].y;
                float d2 = hB[u].x - hB[j].x;
                float d3 = hB[u].y - hB[j].y;
                float q = d0 * d0 + d1 * d1 + d2 * d2 + d3 * d3;
                float dist = __builtin_amdgcn_sqrtf(q);
                float inc = 0.1f * (0.5f * (hB[u].y + hB[j].y)) * dist;
                cinc[k] = inc;
                float wij = (j & 1) ? W2[u][j >> 1].y : W2[u][j >> 1].x;
                wij = clamp01(wij + inc - 0.05f * wij);
                if (j & 1) W2[u][j >> 1].y = wij; else W2[u][j >> 1].x = wij;
            }
        }
        // exchange the 6 incs with the partner lane (DPP)
        float rinc[6];
        #pragma unroll
        for (int k = 0; k < 6; ++k) rinc[k] = dpp_swap1(cinc[k]);
        // apply received incs: pairs u>v; partner computed at its lex(v,u)
        #pragma unroll
        for (int u = 0; u < 4; ++u) {
            #pragma unroll
            for (int v = 0; v < u; ++v) {
                const int k = LEXT[v][u];
                const int j = v + 4;
                float inc = rinc[k];
                float wij = (j & 1) ? W2[u][j >> 1].y : W2[u][j >> 1].x;
                wij = clamp01(wij + inc - 0.05f * wij);
                if (j & 1) W2[u][j >> 1].y = wij; else W2[u][j >> 1].x = wij;
            }
        }
    }

    // ---- h f32 outputs DIRECT from registers (exact): thread owns global
    //      blocks sub*4..sub*4+3 -> 64B at out_h + pos*32 + sub*16
    {
        float* hd = out_h + (size_t)pos * 32 + sub * 16;
        #pragma unroll
        for (int b = 0; b < 4; ++b) {
            float4 v = make_float4(hA[b].x, hA[b].y, hB[b].x, hB[b].y);
            *reinterpret_cast<float4*>(hd + b * 4) = v;
        }
    }
    // ---- W f32 outputs DIRECT: global row co_own+i; own-half pair at byte
    //      col co_own, other-half pair at col co_oth (no selects needed)
    {
        float* wd = out_W + (size_t)pos * 64;
        #pragma unroll
        for (int i = 0; i < 4; ++i) {
            float* rowd = wd + (co_own + i) * 8;
            float4 vo = make_float4(W2[i][0].x, W2[i][0].y, W2[i][1].x, W2[i][1].y);
            float4 vx = make_float4(W2[i][2].x, W2[i][2].y, W2[i][3].x, W2[i][3].y);
            *reinterpret_cast<float4*>(rowd + co_own) = vo;
            *reinterpret_cast<float4*>(rowd + co_oth) = vx;
        }
    }

    // ---- stage phys as f16 into S (for einsum A-fragments only)
    {
        _Float16* sp = S + p * SLD;
        half8 v0, v1;
        v0[0] = (_Float16)hA[0].x; v0[1] = (_Float16)hA[0].y;
        v0[2] = (_Float16)hB[0].x; v0[3] = (_Float16)hB[0].y;
        v0[4] = (_Float16)hA[1].x; v0[5] = (_Float16)hA[1].y;
        v0[6] = (_Float16)hB[1].x; v0[7] = (_Float16)hB[1].y;
        v1[0] = (_Float16)hA[2].x; v1[1] = (_Float16)hA[2].y;
        v1[2] = (_Float16)hB[2].x; v1[3] = (_Float16)hB[2].y;
        v1[4] = (_Float16)hA[3].x; v1[5] = (_Float16)hA[3].y;
        v1[6] = (_Float16)hB[3].x; v1[7] = (_Float16)hB[3].y;
        *reinterpret_cast<half8*>(sp + sub * 16)     = v0;
        *reinterpret_cast<half8*>(sp + sub * 16 + 8) = v1;
        #pragma unroll
        for (int i = 0; i < 4; ++i) {
            half8 wv;
            #pragma unroll
            for (int gc = 0; gc < 8; ++gc) {
                const int lc0 = gc;
                const int lc1 = (gc + 4) & 7;
                float vs0 = (lc0 & 1) ? W2[i][lc0 >> 1].y : W2[i][lc0 >> 1].x;
                float vs1 = (lc1 & 1) ? W2[i][lc1 >> 1].y : W2[i][lc1 >> 1].x;
                wv[gc] = (_Float16)((sub == 0) ? vs0 : vs1);
            }
            *reinterpret_cast<half8*>(sp + 32 + (co_own + i) * 8) = wv;
        }
    }
    __syncthreads();

    // ---- load A fragments for BOTH tiles before S is overlaid by Cbuf
    const int w = tid >> 6, l = tid & 63;
    const int k0q = 4 * (l >> 4);
    half8 afr[2][3];
    #pragma unroll
    for (int t = 0; t < 2; ++t) {
        const int r = t * 64 + w * 16 + (l & 15);
        #pragma unroll
        for (int ks = 0; ks < 3; ++ks) {
            half4 lo = *reinterpret_cast<const half4*>(S + r * SLD + ks * 32 + k0q);
            half4 hi = *reinterpret_cast<const half4*>(S + r * SLD + ks * 32 + 16 + k0q);
            afr[t][ks] = __builtin_shufflevector(lo, hi, 0, 1, 2, 3, 4, 5, 6, 7);
        }
    }
    __syncthreads();   // all S reads done; smem becomes Cbuf

    // ---- einsum per tile; C via padded-LDS transpose, 512B float4 stores
    #pragma unroll
    for (int t = 0; t < 2; ++t) {
        f32x4 acc[16];
        #pragma unroll
        for (int nbv = 0; nbv < 16; ++nbv) acc[nbv] = (f32x4){0.f, 0.f, 0.f, 0.f};
        #pragma unroll
        for (int ks = 0; ks < 3; ++ks) {
            #pragma unroll
            for (int nbv = 0; nbv < 16; ++nbv) {
                half8 b = *reinterpret_cast<const half8*>(Bpre + (size_t)((ks * 16 + nbv) * 64 + l) * 8);
                acc[nbv] = __builtin_amdgcn_mfma_f32_16x16x32_f16(afr[t][ks], b, acc[nbv], 0, 0, 0);
            }
        }
        #pragma unroll
        for (int c = 0; c < 2; ++c) {
            #pragma unroll
            for (int nn = 0; nn < 8; ++nn) {
                const int nbv = c * 8 + nn;
                #pragma unroll
                for (int r = 0; r < 4; ++r) {
                    const int row = w * 16 + 4 * (l >> 4) + r;
                    Cbuf[row * 132 + nn * 16 + (l & 15)] = acc[nbv][r];
                }
            }
            __syncthreads();
            const float4 biasv = reinterpret_cast<const float4*>(lin_b)[c * 32 + (l & 31)];
            #pragma unroll
            for (int rep = 0; rep < 8; ++rep) {
                const int row = w * 16 + rep * 2 + (l >> 5);
                float4 v = *reinterpret_cast<const float4*>(Cbuf + row * 132 + (l & 31) * 4);
                v.x += biasv.x; v.y += biasv.y; v.z += biasv.z; v.w += biasv.w;
                *reinterpret_cast<float4*>(out_emb + (size_t)(pos0 + t * 64 + row) * DM
                                           + c * 128 + (l & 31) * 4) = v;
            }
            __syncthreads();
        }
    }
}

extern "C" void kernel_launch(void* const* d_in, const int* in_sizes, int n_in,
                              void* d_out, int out_size, void* d_ws, size_t ws_size,
                              hipStream_t stream) {
    const int*   bits  = (const int*)d_in[0];
    const float* stim  = (const float*)d_in[1];
    const float* Winit = (const float*)d_in[2];
    const float* lin_w = (const float*)d_in[3];
    const float* lin_b = (const float*)d_in[4];
    const int*   steps = (const int*)d_in[5];

    const int npos = in_sizes[1];   // B*S = 131072

    float* out_emb = (float*)d_out;
    float* out_h   = out_emb + (size_t)npos * DM;
    float* out_W   = out_h + (size_t)npos * 32;
    _Float16* Bpre = (_Float16*)d_ws;            // 48 KB fragment buffer

    hipLaunchKernelGGL(bprep_kernel, dim3(12), dim3(256), 0, stream, lin_w, Bpre);
    hipLaunchKernelGGL(fused_kernel, dim3(npos / 128), dim3(256), 0, stream,
                       bits, stim, Winit, steps, Bpre, lin_b,
                       out_emb, out_h, out_W);
}

// Round 20
// 70.872 us; speedup vs baseline: 1.0871x; 1.0871x over previous
//
#include <hip/hip_runtime.h>

#define NB 8
#define DM 256
#define FD 96
#define SLD 104   // f16 stride of phys staging row (208B, 16B-aligned)

using half8 = _Float16 __attribute__((ext_vector_type(8)));
using half4 = _Float16 __attribute__((ext_vector_type(4)));
using f32x4 = float __attribute__((ext_vector_type(4)));
using f2    = float __attribute__((ext_vector_type(2)));

__device__ __forceinline__ float clamp01(float x) { return fminf(fmaxf(x, 0.0f), 1.0f); }

// lane-xor-1 exchange as DPP quad_perm(1,0,3,2): 1 VALU inst, no LDS/waitcnt.
__device__ __forceinline__ float dpp_swap1(float x) {
    return __builtin_bit_cast(float,
        __builtin_amdgcn_mov_dpp(__builtin_bit_cast(int, x), 0xB1, 0xF, 0xF, true));
}

// ---------------------------------------------------------------------------
// Kernel 0: precompute B = lin_w^T as f16 MFMA fragments into d_ws (48 KB).
// ---------------------------------------------------------------------------
__global__ void bprep_kernel(const float* __restrict__ lin_w,
                             _Float16* __restrict__ Bpre)
{
    const int fb = blockIdx.x * 256 + threadIdx.x;     // 0..3071
    const int ks = fb >> 10, nbv = (fb >> 6) & 15, ll = fb & 63;
    const float* lwrow = lin_w + (size_t)(nbv * 16 + (ll & 15)) * FD
                               + (ks * 32 + 4 * (ll >> 4));
    float4 lo = *reinterpret_cast<const float4*>(lwrow);
    float4 hi = *reinterpret_cast<const float4*>(lwrow + 16);
    half8 v;
    v[0] = (_Float16)lo.x; v[1] = (_Float16)lo.y; v[2] = (_Float16)lo.z; v[3] = (_Float16)lo.w;
    v[4] = (_Float16)hi.x; v[5] = (_Float16)hi.y; v[6] = (_Float16)hi.z; v[7] = (_Float16)hi.w;
    *reinterpret_cast<half8*>(Bpre + (size_t)fb * 8) = v;
}

// ---------------------------------------------------------------------------
// Fused kernel = r18 VERBATIM (71.3us best, absmax 0.0078125) + two
// BIT-IDENTICAL constant folds (safe under fp-contract: pure-mul chains and
// exact x0.5 scalings only):
//   1) 0.1f*(0.5f*(Li+Lj))*dist -> 0.05f*(Li+Lj)*dist   [fl(0.05)=fl(0.1)/2]
//   2) 0.5f*En + 0.5f*Gn       -> 0.5f*(En+Gn)          [halving exact]
// ~320 fewer VALU insts/thread (~7% of sim). r19's med3 + direct-store
// bundle is reverted (regressed 5.7us; LDS-readback path restored).
// ---------------------------------------------------------------------------
__global__ __launch_bounds__(256, 3) void fused_kernel(
    const int* __restrict__ bits,
    const float* __restrict__ stim_in,
    const float* __restrict__ Winit,
    const int* __restrict__ steps_ptr,
    const _Float16* __restrict__ Bpre,
    const float* __restrict__ lin_b,
    float* __restrict__ out_emb,
    float* __restrict__ out_h,
    float* __restrict__ out_W)
{
    __shared__ __align__(16) char smem[64 * 132 * 4];   // 33792 B union
    _Float16* S    = reinterpret_cast<_Float16*>(smem); // [128][SLD] staging
    float*    Cbuf = reinterpret_cast<float*>(smem);    // [64][132] overlay

    const int tid  = threadIdx.x;
    const int pos0 = blockIdx.x * 128;
    const int p    = tid >> 1;
    const int pos  = pos0 + p;
    const int sub  = tid & 1;
    const int steps = steps_ptr[0];

    // local order: blocks 0..3 own half, 4..7 partner half
    f2 hA[8];        // (E,P) per block
    f2 hB[8];        // (G,L) per block
    f2 W2[4][4];     // own 4 rows x 4 local col-pairs

    // ---- decode own 4 blocks
    const int4* bp = reinterpret_cast<const int4*>(bits + (size_t)pos * 64 + sub * 32);
    #pragma unroll
    for (int b = 0; b < 4; ++b) {
        int4 lo = bp[2 * b + 0];
        int4 hi = bp[2 * b + 1];
        hA[b].x = (float)(lo.x * 2 + lo.y) / 3.0f;
        hA[b].y = (float)(lo.z * 2 + lo.w) / 3.0f;
        hB[b].x = (float)(hi.x * 2 + hi.y) / 3.0f;
        hB[b].y = (float)(hi.z * 2 + hi.w) / 3.0f;
    }
    #pragma unroll
    for (int b = 0; b < 4; ++b) {
        hA[4 + b].x = dpp_swap1(hA[b].x);
        hA[4 + b].y = dpp_swap1(hA[b].y);
        hB[4 + b].x = dpp_swap1(hB[b].x);
        hB[4 + b].y = dpp_swap1(hB[b].y);
    }

    const int co_own = sub * 4;
    const int co_oth = 4 - sub * 4;
    #pragma unroll
    for (int i = 0; i < 4; ++i) {
        const float* rowp = Winit + (size_t)pos * 64 + (size_t)(co_own + i) * 8;
        float4 a = *reinterpret_cast<const float4*>(rowp + co_own);
        float4 b = *reinterpret_cast<const float4*>(rowp + co_oth);
        W2[i][0] = (f2){a.x, a.y};
        W2[i][1] = (f2){a.z, a.w};
        W2[i][2] = (f2){b.x, b.y};
        W2[i][3] = (f2){b.z, b.w};
        if (i & 1) W2[i][i >> 1].y = 0.0f; else W2[i][i >> 1].x = 0.0f;  // diag
    }

    const float stim = stim_in[pos];

    // lex index of (a,b), a<b, in 0..3 (folds at compile time under unroll)
    constexpr int LEXT[4][4] = {{9,0,1,2},{9,9,3,4},{9,9,9,5},{9,9,9,9}};

    for (int st = 0; st < steps; ++st) {
        // ---- neigh: packed fma chains, per-channel order j=0..7 (== r14)
        f2 nbA[4], nbB[4];
        #pragma unroll
        for (int i = 0; i < 4; ++i) {
            f2 sA = {0.f, 0.f}, sB = {0.f, 0.f};
            #pragma unroll
            for (int jc = 0; jc < 4; ++jc) {
                f2 wv = W2[i][jc];
                f2 w0 = {wv.x, wv.x};
                f2 w1 = {wv.y, wv.y};
                sA = __builtin_elementwise_fma(w0, hA[2 * jc],     sA);
                sA = __builtin_elementwise_fma(w1, hA[2 * jc + 1], sA);
                sB = __builtin_elementwise_fma(w0, hB[2 * jc],     sB);
                sB = __builtin_elementwise_fma(w1, hB[2 * jc + 1], sB);
            }
            float tw = W2[i][0].x; tw += W2[i][0].y;
            tw += W2[i][1].x;      tw += W2[i][1].y;
            tw += W2[i][2].x;      tw += W2[i][2].y;
            tw += W2[i][3].x;      tw += W2[i][3].y;
            float inv = __builtin_amdgcn_rcpf(tw + 1e-8f);
            f2 inv2 = {inv, inv};
            nbA[i] = sA * inv2;
            nbB[i] = sB * inv2;
        }
        // ---- h update (scalar; 'good' fold is bit-exact)
        #pragma unroll
        for (int i = 0; i < 4; ++i) {
            float E = hA[i].x, P = hA[i].y, G = hB[i].x, L = hB[i].y;
            float En = nbA[i].x, Pn = nbA[i].y, Gn = nbB[i].x, Ln = nbB[i].y;
            float E_new = clamp01(E + 0.3f * stim - 0.4f * P - 0.2f * G);
            float P_new = clamp01(P + 0.5f * stim + 0.3f * (Pn - P) - 0.2f * E);
            float G_new = clamp01(G + 0.4f * E * (1.0f - P) + 0.2f * (Gn - G) - 0.3f * P);
            float good  = 0.5f * (En + Gn);
            float L_new = clamp01(L + 0.4f * good + 0.3f * (Ln - L) - 0.3f * P);
            hA[i] = (f2){E_new, P_new};
            hB[i] = (f2){G_new, L_new};
        }
        // mirror partner's updated half (DPP, VALU-only)
        #pragma unroll
        for (int b = 0; b < 4; ++b) {
            hA[4 + b].x = dpp_swap1(hA[b].x);
            hA[4 + b].y = dpp_swap1(hA[b].y);
            hB[4 + b].x = dpp_swap1(hB[b].x);
            hB[4 + b].y = dpp_swap1(hB[b].y);
        }

        // ---- W update (every entry updated once; incs bit-identical)
        // (a) intra-half pairs: 6, both sides owned
        #pragma unroll
        for (int i = 0; i < 4; ++i) {
            #pragma unroll
            for (int j = i + 1; j < 4; ++j) {
                float d0 = hA[i].x - hA[j].x;
                float d1 = hA[i].y - hA[j].y;
                float d2 = hB[i].x - hB[j].x;
                float d3 = hB[i].y - hB[j].y;
                float q = d0 * d0 + d1 * d1 + d2 * d2 + d3 * d3;
                float dist = __builtin_amdgcn_sqrtf(q);
                float inc = 0.05f * (hB[i].y + hB[j].y) * dist;
                float wij = (j & 1) ? W2[i][j >> 1].y : W2[i][j >> 1].x;
                wij = clamp01(wij + inc - 0.05f * wij);
                if (j & 1) W2[i][j >> 1].y = wij; else W2[i][j >> 1].x = wij;
                float wji = (i & 1) ? W2[j][i >> 1].y : W2[j][i >> 1].x;
                wji = clamp01(wji + inc - 0.05f * wji);
                if (i & 1) W2[j][i >> 1].y = wji; else W2[j][i >> 1].x = wji;
            }
        }
        // (b) cross diagonal (u, u+4): same global pair on both lanes
        #pragma unroll
        for (int u = 0; u < 4; ++u) {
            const int j = u + 4;
            float d0 = hA[u].x - hA[j].x;
            float d1 = hA[u].y - hA[j].y;
            float d2 = hB[u].x - hB[j].x;
            float d3 = hB[u].y - hB[j].y;
            float q = d0 * d0 + d1 * d1 + d2 * d2 + d3 * d3;
            float dist = __builtin_amdgcn_sqrtf(q);
            float inc = 0.05f * (hB[u].y + hB[j].y) * dist;
            float wij = (j & 1) ? W2[u][j >> 1].y : W2[u][j >> 1].x;
            wij = clamp01(wij + inc - 0.05f * wij);
            if (j & 1) W2[u][j >> 1].y = wij; else W2[u][j >> 1].x = wij;
        }
        // (c) cross off-diagonal: compute u<v (6), update own row, keep inc
        float cinc[6];
        #pragma unroll
        for (int u = 0; u < 4; ++u) {
            #pragma unroll
            for (int v = u + 1; v < 4; ++v) {
                const int k = LEXT[u][v];
                const int j = v + 4;
                float d0 = hA[u].x - hA[j].x;
                float d1 = hA[u].y - hA[j].y;
                float d2 = hB[u].x - hB[j].x;
                float d3 = hB[u].y - hB[j].y;
                float q = d0 * d0 + d1 * d1 + d2 * d2 + d3 * d3;
                float dist = __builtin_amdgcn_sqrtf(q);
                float inc = 0.05f * (hB[u].y + hB[j].y) * dist;
                cinc[k] = inc;
                float wij = (j & 1) ? W2[u][j >> 1].y : W2[u][j >> 1].x;
                wij = clamp01(wij + inc - 0.05f * wij);
                if (j & 1) W2[u][j >> 1].y = wij; else W2[u][j >> 1].x = wij;
            }
        }
        // exchange the 6 incs with the partner lane (DPP)
        float rinc[6];
        #pragma unroll
        for (int k = 0; k < 6; ++k) rinc[k] = dpp_swap1(cinc[k]);
        // apply received incs: pairs u>v; partner computed at its lex(v,u)
        #pragma unroll
        for (int u = 0; u < 4; ++u) {
            #pragma unroll
            for (int v = 0; v < u; ++v) {
                const int k = LEXT[v][u];
                const int j = v + 4;
                float inc = rinc[k];
                float wij = (j & 1) ? W2[u][j >> 1].y : W2[u][j >> 1].x;
                wij = clamp01(wij + inc - 0.05f * wij);
                if (j & 1) W2[u][j >> 1].y = wij; else W2[u][j >> 1].x = wij;
            }
        }
    }

    // ---- stage phys as f16 into S (identical to r18)
    {
        _Float16* sp = S + p * SLD;
        half8 v0, v1;
        v0[0] = (_Float16)hA[0].x; v0[1] = (_Float16)hA[0].y;
        v0[2] = (_Float16)hB[0].x; v0[3] = (_Float16)hB[0].y;
        v0[4] = (_Float16)hA[1].x; v0[5] = (_Float16)hA[1].y;
        v0[6] = (_Float16)hB[1].x; v0[7] = (_Float16)hB[1].y;
        v1[0] = (_Float16)hA[2].x; v1[1] = (_Float16)hA[2].y;
        v1[2] = (_Float16)hB[2].x; v1[3] = (_Float16)hB[2].y;
        v1[4] = (_Float16)hA[3].x; v1[5] = (_Float16)hA[3].y;
        v1[6] = (_Float16)hB[3].x; v1[7] = (_Float16)hB[3].y;
        *reinterpret_cast<half8*>(sp + sub * 16)     = v0;
        *reinterpret_cast<half8*>(sp + sub * 16 + 8) = v1;
        #pragma unroll
        for (int i = 0; i < 4; ++i) {
            half8 wv;
            #pragma unroll
            for (int gc = 0; gc < 8; ++gc) {
                const int lc0 = gc;
                const int lc1 = (gc + 4) & 7;
                float vs0 = (lc0 & 1) ? W2[i][lc0 >> 1].y : W2[i][lc0 >> 1].x;
                float vs1 = (lc1 & 1) ? W2[i][lc1 >> 1].y : W2[i][lc1 >> 1].x;
                wv[gc] = (_Float16)((sub == 0) ? vs0 : vs1);
            }
            *reinterpret_cast<half8*>(sp + 32 + (co_own + i) * 8) = wv;
        }
    }
    __syncthreads();

    // ---- h/W f32 outputs: wide readback (ds_read_b64 + float4 stores)
    #pragma unroll
    for (int i = 0; i < 4; ++i) {
        const int flat4 = i * 1024 + tid * 4;
        const int row = flat4 >> 5, feat = flat4 & 31;
        half4 v = *reinterpret_cast<const half4*>(S + row * SLD + feat);
        float4 o = make_float4((float)v[0], (float)v[1], (float)v[2], (float)v[3]);
        *reinterpret_cast<float4*>(out_h + (size_t)pos0 * 32 + flat4) = o;
    }
    #pragma unroll
    for (int i = 0; i < 8; ++i) {
        const int flat4 = i * 1024 + tid * 4;
        const int row = flat4 >> 6, feat = flat4 & 63;
        half4 v = *reinterpret_cast<const half4*>(S + row * SLD + 32 + feat);
        float4 o = make_float4((float)v[0], (float)v[1], (float)v[2], (float)v[3]);
        *reinterpret_cast<float4*>(out_W + (size_t)pos0 * 64 + flat4) = o;
    }

    // ---- load A fragments for BOTH tiles before S is overlaid by Cbuf
    const int w = tid >> 6, l = tid & 63;
    const int k0q = 4 * (l >> 4);
    half8 afr[2][3];
    #pragma unroll
    for (int t = 0; t < 2; ++t) {
        const int r = t * 64 + w * 16 + (l & 15);
        #pragma unroll
        for (int ks = 0; ks < 3; ++ks) {
            half4 lo = *reinterpret_cast<const half4*>(S + r * SLD + ks * 32 + k0q);
            half4 hi = *reinterpret_cast<const half4*>(S + r * SLD + ks * 32 + 16 + k0q);
            afr[t][ks] = __builtin_shufflevector(lo, hi, 0, 1, 2, 3, 4, 5, 6, 7);
        }
    }
    __syncthreads();   // all S reads done; smem becomes Cbuf

    // ---- einsum per tile; C via padded-LDS transpose, 512B float4 stores
    #pragma unroll
    for (int t = 0; t < 2; ++t) {
        f32x4 acc[16];
        #pragma unroll
        for (int nbv = 0; nbv < 16; ++nbv) acc[nbv] = (f32x4){0.f, 0.f, 0.f, 0.f};
        #pragma unroll
        for (int ks = 0; ks < 3; ++ks) {
            #pragma unroll
            for (int nbv = 0; nbv < 16; ++nbv) {
                half8 b = *reinterpret_cast<const half8*>(Bpre + (size_t)((ks * 16 + nbv) * 64 + l) * 8);
                acc[nbv] = __builtin_amdgcn_mfma_f32_16x16x32_f16(afr[t][ks], b, acc[nbv], 0, 0, 0);
            }
        }
        #pragma unroll
        for (int c = 0; c < 2; ++c) {
            #pragma unroll
            for (int nn = 0; nn < 8; ++nn) {
                const int nbv = c * 8 + nn;
                #pragma unroll
                for (int r = 0; r < 4; ++r) {
                    const int row = w * 16 + 4 * (l >> 4) + r;
                    Cbuf[row * 132 + nn * 16 + (l & 15)] = acc[nbv][r];
                }
            }
            __syncthreads();
            const float4 biasv = reinterpret_cast<const float4*>(lin_b)[c * 32 + (l & 31)];
            #pragma unroll
            for (int rep = 0; rep < 8; ++rep) {
                const int row = w * 16 + rep * 2 + (l >> 5);
                float4 v = *reinterpret_cast<const float4*>(Cbuf + row * 132 + (l & 31) * 4);
                v.x += biasv.x; v.y += biasv.y; v.z += biasv.z; v.w += biasv.w;
                *reinterpret_cast<float4*>(out_emb + (size_t)(pos0 + t * 64 + row) * DM
                                           + c * 128 + (l & 31) * 4) = v;
            }
            __syncthreads();
        }
    }
}

extern "C" void kernel_launch(void* const* d_in, const int* in_sizes, int n_in,
                              void* d_out, int out_size, void* d_ws, size_t ws_size,
                              hipStream_t stream) {
    const int*   bits  = (const int*)d_in[0];
    const float* stim  = (const float*)d_in[1];
    const float* Winit = (const float*)d_in[2];
    const float* lin_w = (const float*)d_in[3];
    const float* lin_b = (const float*)d_in[4];
    const int*   steps = (const int*)d_in[5];

    const int npos = in_sizes[1];   // B*S = 131072

    float* out_emb = (float*)d_out;
    float* out_h   = out_emb + (size_t)npos * DM;
    float* out_W   = out_h + (size_t)npos * 32;
    _Float16* Bpre = (_Float16*)d_ws;            // 48 KB fragment buffer

    hipLaunchKernelGGL(bprep_kernel, dim3(12), dim3(256), 0, stream, lin_w, Bpre);
    hipLaunchKernelGGL(fused_kernel, dim3(npos / 128), dim3(256), 0, stream,
                       bits, stim, Winit, steps, Bpre, lin_b,
                       out_emb, out_h, out_W);
}